// Round 5
// baseline (486.954 us; speedup 1.0000x reference)
//
#include <hip/hip_runtime.h>
#include <math.h>

// B=2, N=131072 (=2^17), K=9, P=4, D=4, S=1, CI=8, CO=8
// Design: 1 lane = 1 point. x gathered ONCE into regs (no 16x broadcast dup),
// amp via wave-uniform s_load (scalar pipe), zero LDS, zero barriers.
#define N_PTS 131072
#define KNB   9
#define PDN   16
#define CIN   8
#define COUT  8
#define THREADS 64

typedef float vf4  __attribute__((ext_vector_type(4)));
typedef float vf4u __attribute__((ext_vector_type(4), aligned(4)));
typedef int   vi4u __attribute__((ext_vector_type(4), aligned(4)));

__global__ __launch_bounds__(THREADS, 4) void polnormal_kernel(
    const float* __restrict__ x,      // (B, N, CI)
    const float* __restrict__ dx,     // (B, N, K)
    const float* __restrict__ dy,     // (B, N, K)
    const int*   __restrict__ adj,    // (N, K)
    const float* __restrict__ phis,   // (P,)
    const float* __restrict__ dists,  // (D,)
    const float* __restrict__ sigma,  // (S,)
    const float* __restrict__ amp,    // (P, D, S, CI, CO) = (pd, c, o)
    float*       __restrict__ out)    // (B, N, P, D, S, CO)
{
    const int pt = blockIdx.x * THREADS + threadIdx.x;   // 0..262143 (flattened b,n)
    const int b  = pt >> 17;                             // N = 2^17
    const int n  = pt & (N_PTS - 1);

    // ---- adj: 9 ints (4-B-aligned vector loads)
    const int* ap = adj + (long)n * KNB;
    vi4u a03 = *(const vi4u*)ap;
    vi4u a47 = *(const vi4u*)(ap + 4);
    int  a8  = ap[8];
    int rows[KNB] = {a03.x, a03.y, a03.z, a03.w, a47.x, a47.y, a47.z, a47.w, a8};

    // ---- gather x rows: 18 independent 16-B loads, all in flight, 1x (no dup)
    const vf4* xb = (const vf4*)x + (long)b * (N_PTS * 2);
    vf4 xlo[KNB], xhi[KNB];
#pragma unroll
    for (int k = 0; k < KNB; ++k) {
        long r2i = (long)rows[k] * 2;
        xlo[k] = xb[r2i];
        xhi[k] = xb[r2i + 1];
    }

    // ---- dx/dy: 9 floats each (4-B-aligned vector loads)
    const float* dxp = dx + (long)pt * KNB;
    const float* dyp = dy + (long)pt * KNB;
    vf4u dxa = *(const vf4u*)dxp, dxb2 = *(const vf4u*)(dxp + 4);
    vf4u dya = *(const vf4u*)dyp, dyb2 = *(const vf4u*)(dyp + 4);
    float dxv[KNB] = {dxa.x, dxa.y, dxa.z, dxa.w, dxb2.x, dxb2.y, dxb2.z, dxb2.w, dxp[8]};
    float dyv[KNB] = {dya.x, dya.y, dya.z, dya.w, dyb2.x, dyb2.y, dyb2.z, dyb2.w, dyp[8]};

    // ---- uniform params (s_load path)
    const float sig  = fmaxf(sigma[0], 1e-10f);
    const float s2   = sig * sig;
    const float k2   = (-0.5f / s2) * 1.4426950408889634f;   // exp(a)=exp2(a*log2e)
    const float norm = rsqrtf(6.283185307179586f * s2);

    float* op = out + (long)pt * (PDN * COUT);

#pragma unroll
    for (int pd = 0; pd < PDN; ++pd) {
        const int p = pd >> 2, d = pd & 3;
        // phis/dists are wave-uniform s_loads, CSE'd across iterations;
        // sincos recomputed per iter (2 trans) to avoid dynamic reg indexing.
        float sn, cs;
        __sincosf(phis[p], &sn, &cs);
        const float dist = dists[d];
        const float mux = cs * dist, muy = sn * dist;

        float w[KNB];
#pragma unroll
        for (int k = 0; k < KNB; ++k) {
            float ddx = dxv[k] - mux;
            float ddy = dyv[k] - muy;
            w[k] = __builtin_amdgcn_exp2f(k2 * __builtin_fmaf(ddx, ddx, ddy * ddy));
        }

        vf4 wxA = {0.f, 0.f, 0.f, 0.f}, wxB = {0.f, 0.f, 0.f, 0.f};
#pragma unroll
        for (int k = 0; k < KNB; ++k) {
            wxA += w[k] * xlo[k];
            wxB += w[k] * xhi[k];
        }

        const float wxs[CIN] = {wxA.x, wxA.y, wxA.z, wxA.w,
                                wxB.x, wxB.y, wxB.z, wxB.w};
        vf4 accA = {0.f, 0.f, 0.f, 0.f}, accB = {0.f, 0.f, 0.f, 0.f};
        const float* ar = amp + pd * (CIN * COUT);
#pragma unroll
        for (int c = 0; c < CIN; ++c) {
            vf4 ampA = *(const vf4*)(ar + c * COUT);       // uniform addr -> s_load
            vf4 ampB = *(const vf4*)(ar + c * COUT + 4);
            accA += wxs[c] * ampA;
            accB += wxs[c] * ampB;
        }

        // 32 B/lane; lane fills its point's 512 B across 16 pd iters (L2 merges)
        __builtin_nontemporal_store(accA * norm, (vf4*)(op + pd * COUT));
        __builtin_nontemporal_store(accB * norm, (vf4*)(op + pd * COUT + 4));
    }
}

extern "C" void kernel_launch(void* const* d_in, const int* in_sizes, int n_in,
                              void* d_out, int out_size, void* d_ws, size_t ws_size,
                              hipStream_t stream) {
    const float* x     = (const float*)d_in[0];
    const float* dx    = (const float*)d_in[1];
    const float* dy    = (const float*)d_in[2];
    const int*   adj   = (const int*)  d_in[3];
    const float* phis  = (const float*)d_in[4];
    const float* dists = (const float*)d_in[5];
    const float* sigma = (const float*)d_in[6];
    const float* amp   = (const float*)d_in[7];
    float* out = (float*)d_out;

    const int total_pts = 2 * N_PTS;              // 262144
    const int grid = total_pts / THREADS;         // 4096 single-wave blocks
    polnormal_kernel<<<grid, THREADS, 0, stream>>>(x, dx, dy, adj, phis, dists,
                                                   sigma, amp, out);
}